// Round 8
// baseline (263.912 us; speedup 1.0000x reference)
//
#include <hip/hip_runtime.h>

#define SSIM_H 512
#define SSIM_W 512
#define PLANES 96
#define TILE_W 64
#define TILE_H 32
#define GRID_X (SSIM_W / TILE_W)   // 8
#define GRID_Y (SSIM_H / TILE_H)   // 16
#define TOTAL_BLOCKS (GRID_X * GRID_Y * PLANES)  // 12288
#define N_TOTAL 25165824.0

// Raw staging: per image 44 rows (tr0-5..tr0+38), row stride 90 dwords,
// payload 84 dwords (cols tc0-8..tc0+75) starting at dword 90r+2.
//  * stride 90 -> bank phase (90r+2)%32 = (26r+2)%32: 16 DISTINCT phases
//    across the 16 m-rows a wave reads -> ~4-way worst (1.58x), no R6-style
//    blowup.
//  * payload start +2 keeps b64 reads aligned (all read dwords even).
//  * 2*44*90 = 7920 dwords = 1980 16B chunks; LDS dest of chunk c is
//    byte 16*c (990 chunks per image: 990*16 = 15840 = image stride. The
//    flat chunk-linear layout IS the [img][row][90] layout.)
#define RAW_DW_IMG 3960
#define RAW_CHUNKS 1980

typedef _Float16 half4v __attribute__((ext_vector_type(4)));
typedef _Float16 half8v __attribute__((ext_vector_type(8)));
typedef float float4v __attribute__((ext_vector_type(4)));

struct __align__(8) f2 { float x, y; };

// Gaussian tap k (0..10), sigma=1.5: exp(-(k-5)^2/4.5) / 3.759233
__device__ __forceinline__ float gwf(int k) {
  const float d = (float)(k - 5);
  return __expf(-d * d / 4.5f) * 0.26601171702936207f;
}

// Round-8 (chain attack, done right): R1-R3 proved register prefetch is
// un-winnable (RA sinks or AGPR-spills it). R6 proved LDS staging works
// but paid +50 inst/thread unpack, 8.5M bank conflicts, and an occupancy
// level. This version stages HBM->LDS with global_load_lds (no VGPR
// transit at all -> nothing to sink/spill), ONE vmcnt(0) drain = one
// global round trip per block, 16-phase bank layout, 3 blocks/CU.
// Per-pixel math identical to R7 (absmax 0.0 path); R6's verified
// edge-masking; TILE_H=32 geometry.
__global__ __launch_bounds__(256, 3)
void ssim_l1_kernel(const float* __restrict__ pred,
                    const float* __restrict__ targ,
                    f2* __restrict__ partials) {
  __shared__ unsigned int RawU[2 * RAW_DW_IMG];  // 31,680 B
  __shared__ _Float16 Hs[4][64][44];             // 22,528 B
  __shared__ float red[2][4];                    // total 54,240 -> 3/CU

  const int tid = (int)threadIdx.x;
  const int wv = tid >> 6;    // wave: owns col-group wv in BOTH stages
  const int lane = tid & 63;
  const int q = lane >> 4;    // quad
  const int m = lane & 15;

  const int tr0 = (int)blockIdx.y * TILE_H;
  const int tc0 = (int)blockIdx.x * TILE_W;
  const size_t pbase = (size_t)blockIdx.z * (SSIM_H * SSIM_W);
  const float* __restrict__ xp = pred + pbase;
  const float* __restrict__ yp = targ + pbase;

  // ---- Staging: 1980 chunks via global_load_lds (8 issues/thread) -------
  // chunk c: img = c/990, t = 4*(c%990), r = t/90, w = t-90r.
  // LDS dest is implicit: wave-uniform base + lane*16 = byte 16*c.
  // Global src: row clamp(tr0-5+r), col clamp(tc0-10+w) (payload dword
  // 90r+2 <-> col tc0-8  =>  row-dword w <-> col tc0-10+w).
#pragma unroll
  for (int k = 0; k < 8; ++k) {
    const int c = k * 256 + tid;
    if (c < RAW_CHUNKS) {
      const int img = (c >= 990);
      const int cc = c - (img ? 990 : 0);
      const int t = cc << 2;
      const int r = (int)(((unsigned)t * 46604u) >> 22);  // t/90, t<3960
      const int w = t - 90 * r;
      int gr = tr0 - 5 + r;
      gr = gr < 0 ? 0 : (gr > 511 ? 511 : gr);
      int gc = w + (tc0 - 10);
      gc = gc < 0 ? 0 : (gc > 508 ? 508 : gc);
      const float* src = (img ? yp : xp) + ((size_t)gr << 9) + gc;
      __builtin_amdgcn_global_load_lds(
          (const __attribute__((address_space(1))) unsigned int*)src,
          (__attribute__((address_space(3))) unsigned int*)
              ((char*)RawU + (k << 12) + ((tid >> 6) << 10)),
          16, 0, 0);
    }
  }

  // ---- Edge patch: chunks straddling col 0 / col 511 are mis-clamped
  // (payload phase +2 vs 16B grid). Only cols {0,1} (tc0==0) or
  // {510,511} (tc0==448) are affected; load them directly (issued before
  // the same drain) and ds_write after it.
  const bool xl = (tc0 == 0), xr = (tc0 == SSIM_W - TILE_W);
  f2 patch;
  bool dop = false;
  int pD = 0;
  if ((xl | xr) && tid < 88) {
    dop = true;
    const int pim = tid >= 44;
    const int r = tid - (pim ? 44 : 0);
    int gr = tr0 - 5 + r;
    gr = gr < 0 ? 0 : (gr > 511 ? 511 : gr);
    const int cL = xl ? 0 : 510;
    patch = *(const f2*)((pim ? yp : xp) + ((size_t)gr << 9) + cL);
    pD = pim * RAW_DW_IMG + 90 * r + 2 + (cL - (tc0 - 8));
  }

  // Per-lane banded weight fragment (overlaps the in-flight staging).
  half8v wf;
#pragma unroll
  for (int j = 0; j < 8; ++j) {
    const int k = 8 * q + j - m;
    const float v = (k >= 0 && k <= 10) ? gwf(k) : 0.0f;
    wf[j] = (_Float16)v;
  }

  // ---- ONE drain for the whole tile (the only global round trip).
  asm volatile("s_waitcnt vmcnt(0)" ::: "memory");
  if (dop) *(f2*)&RawU[pD] = patch;
  __syncthreads();

  const int cw = tc0 + 16 * wv;      // wave's output col-group (global)
  const int cbase = cw - 5 + 8 * q;  // first of 8 raw cols for this lane
  const bool yedge = (tr0 == 0) || (tr0 == SSIM_H - TILE_H);

  float l1 = 0.0f;

  // ---------------- Stage 1: horizontal conv -> Hs (LDS-fed) -------------
  // Read dword B = 90*rs + 16wv + 8q + 4; dword B+1+j <-> col cbase+j.
  const int Bbase = 16 * wv + 8 * q + 4;
#pragma unroll
  for (int rg = 0; rg < 3; ++rg) {
    const int r = rg * 16 + m;          // H row index
    const int rs = r < 43 ? r : 43;     // rows 44-47: valid reads, discarded
    const float* Rx = (const float*)RawU + 90 * rs + Bbase;
    const float* Ry = Rx + RAW_DW_IMG;
    f2 a0 = *(const f2*)Rx;
    f2 a1 = *(const f2*)(Rx + 2);
    f2 a2 = *(const f2*)(Rx + 4);
    f2 a3 = *(const f2*)(Rx + 6);
    float a4 = Rx[8];
    f2 b0 = *(const f2*)Ry;
    f2 b1 = *(const f2*)(Ry + 2);
    f2 b2 = *(const f2*)(Ry + 4);
    f2 b3 = *(const f2*)(Ry + 6);
    float b4 = Ry[8];
    float xf[8] = {a0.y, a1.x, a1.y, a2.x, a2.y, a3.x, a3.y, a4};
    float yf[8] = {b0.y, b1.x, b1.y, b2.x, b2.y, b3.x, b3.y, b4};

    if (yedge) {  // zero out-of-image rows (matches reference zero-pad)
      const bool okr = (unsigned)(tr0 - 5 + r) < (unsigned)SSIM_H;
#pragma unroll
      for (int j = 0; j < 8; ++j) {
        xf[j] = okr ? xf[j] : 0.0f;
        yf[j] = okr ? yf[j] : 0.0f;
      }
    }
    if (xl | xr) {  // zero out-of-image cols
#pragma unroll
      for (int j = 0; j < 8; ++j) {
        const bool ok = (unsigned)(cbase + j) < (unsigned)SSIM_W;
        xf[j] = ok ? xf[j] : 0.0f;
        yf[j] = ok ? yf[j] : 0.0f;
      }
    }

    // Exact fp32 L1 on core pixels, counted exactly once:
    // core rows hr in [5, 5+TILE_H), core cols k = 8q+j in [5,21).
    if (r >= 5 && r < 5 + TILE_H) {
#pragma unroll
      for (int j = 0; j < 8; ++j) {
        const int k = 8 * q + j;
        if (k >= 5 && k < 21) l1 += fabsf(xf[j] - yf[j]);
      }
    }

    // f16 A-frags: x, y converted; derived planes in packed f16 math.
    half8v ax, ay;
#pragma unroll
    for (int j = 0; j < 8; ++j) {
      ax[j] = (_Float16)xf[j];
      ay[j] = (_Float16)yf[j];
    }
    half8v axxyy = ax * ax + ay * ay;
    half8v axy = ax * ay;

    const float4v z = {0.0f, 0.0f, 0.0f, 0.0f};
    float4v c0 = __builtin_amdgcn_mfma_f32_16x16x32_f16(ax,    wf, z, 0, 0, 0);
    float4v c1 = __builtin_amdgcn_mfma_f32_16x16x32_f16(ay,    wf, z, 0, 0, 0);
    float4v c2 = __builtin_amdgcn_mfma_f32_16x16x32_f16(axxyy, wf, z, 0, 0, 0);
    float4v c3 = __builtin_amdgcn_mfma_f32_16x16x32_f16(axy,   wf, z, 0, 0, 0);

    // C layout: col=lane&15, row=4q+reg (rows contiguous -> one b64/plane).
    // Skip rg=2,q=3 (rows 44-47): beyond the 44-row array, never read.
    if (rg != 2 || q != 3) {
      const int hcol = 16 * wv + m;
      const int hrow = rg * 16 + 4 * q;
      half4v h;
      h[0] = (_Float16)c0[0]; h[1] = (_Float16)c0[1];
      h[2] = (_Float16)c0[2]; h[3] = (_Float16)c0[3];
      *(half4v*)&Hs[0][hcol][hrow] = h;
      h[0] = (_Float16)c1[0]; h[1] = (_Float16)c1[1];
      h[2] = (_Float16)c1[2]; h[3] = (_Float16)c1[3];
      *(half4v*)&Hs[1][hcol][hrow] = h;
      h[0] = (_Float16)c2[0]; h[1] = (_Float16)c2[1];
      h[2] = (_Float16)c2[2]; h[3] = (_Float16)c2[3];
      *(half4v*)&Hs[2][hcol][hrow] = h;
      h[0] = (_Float16)c3[0]; h[1] = (_Float16)c3[1];
      h[2] = (_Float16)c3[2]; h[3] = (_Float16)c3[3];
      *(half4v*)&Hs[3][hcol][hrow] = h;
    }
  }

  // Wave-private H dependency: this wave's ds_writes only (stage 2 reads
  // only the column slab this wave wrote). sched_barrier per rule #18.
  asm volatile("s_waitcnt lgkmcnt(0)" ::: "memory");
  __builtin_amdgcn_sched_barrier(0);

  // ---------------- Stage 2: vertical conv + SSIM (wave-private) ----------
  float ssim = 0.0f;
  {
    const int hcol = 16 * wv + m;  // B-frag col n = lane&15, own slab
    half8v bfr[2][4];
#pragma unroll
    for (int rb = 0; rb < 2; ++rb) {
      const int hrow = 16 * rb + 8 * q;  // window row base (band = rb)
      // hi half reads rows hrow+4..hrow+7; rb=1,q=3 would be rows 44-47
      // whose taps are identically zero -> clamp to 40 (bit-exact).
      const int hrow_hi = (hrow + 4 <= 40) ? hrow + 4 : 40;
#pragma unroll
      for (int p = 0; p < 4; ++p) {
        half4v lo = *(const half4v*)&Hs[p][hcol][hrow];
        half4v hi = *(const half4v*)&Hs[p][hcol][hrow_hi];
        bfr[rb][p] = __builtin_shufflevector(lo, hi, 0, 1, 2, 3, 4, 5, 6, 7);
      }
    }
    const float C1v = 1.0e-4f, C2v = 9.0e-4f;
#pragma unroll
    for (int rb = 0; rb < 2; ++rb) {
      const float4v z = {0.0f, 0.0f, 0.0f, 0.0f};
      float4v acc[4];
#pragma unroll
      for (int p = 0; p < 4; ++p)
        acc[p] = __builtin_amdgcn_mfma_f32_16x16x32_f16(wf, bfr[rb][p], z,
                                                        0, 0, 0);
#pragma unroll
      for (int r = 0; r < 4; ++r) {
        const float mu1 = acc[0][r], mu2 = acc[1][r];
        const float exxyy = acc[2][r], exy = acc[3][r];
        const float m11 = mu1 * mu1, m22 = mu2 * mu2, m12 = mu1 * mu2;
        const float num = (2.0f * m12 + C1v) * (2.0f * (exy - m12) + C2v);
        const float den = (m11 + m22 + C1v) *
                          ((exxyy - m11 - m22) + C2v);
        ssim += num / den;
      }
    }
  }

  // ---- Reduction: wave shuffle -> LDS -> block -> private partial slot ----
  float v0 = l1, v1 = ssim;
#pragma unroll
  for (int off = 32; off > 0; off >>= 1) {
    v0 += __shfl_down(v0, off, 64);
    v1 += __shfl_down(v1, off, 64);
  }
  if (lane == 0) { red[0][wv] = v0; red[1][wv] = v1; }
  __syncthreads();
  if (tid == 0) {
    f2 s;
    s.x = red[0][0] + red[0][1] + red[0][2] + red[0][3];
    s.y = red[1][0] + red[1][1] + red[1][2] + red[1][3];
    const int bid = ((int)blockIdx.z * GRID_Y + (int)blockIdx.y) * GRID_X +
                    (int)blockIdx.x;
    partials[bid] = s;
  }
}

__global__ __launch_bounds__(256)
void finalize_kernel(const f2* __restrict__ partials,
                     float* __restrict__ out) {
  __shared__ double red[2][4];
  const int tid = (int)threadIdx.x;
  double L = 0.0, S = 0.0;
  for (int i = tid; i < TOTAL_BLOCKS; i += 256) {
    const f2 v = partials[i];
    L += (double)v.x;
    S += (double)v.y;
  }
#pragma unroll
  for (int off = 32; off > 0; off >>= 1) {
    L += __shfl_down(L, off, 64);
    S += __shfl_down(S, off, 64);
  }
  const int lane = tid & 63, wid = tid >> 6;
  if (lane == 0) { red[0][wid] = L; red[1][wid] = S; }
  __syncthreads();
  if (tid == 0) {
    const double Ls = red[0][0] + red[0][1] + red[0][2] + red[0][3];
    const double Ss = red[1][0] + red[1][1] + red[1][2] + red[1][3];
    const double invN = 1.0 / N_TOTAL;
    out[0] = (float)(0.84 * (Ls * invN) + 0.16 * (1.0 - Ss * invN));
  }
}

extern "C" void kernel_launch(void* const* d_in, const int* in_sizes, int n_in,
                              void* d_out, int out_size, void* d_ws, size_t ws_size,
                              hipStream_t stream) {
  const float* pred = (const float*)d_in[0];
  const float* targ = (const float*)d_in[1];
  float* out = (float*)d_out;
  f2* partials = (f2*)d_ws;  // 12288 * 8 B = 96 KB

  dim3 grid(GRID_X, GRID_Y, PLANES);  // (8, 16, 96)
  ssim_l1_kernel<<<grid, 256, 0, stream>>>(pred, targ, partials);
  finalize_kernel<<<1, 256, 0, stream>>>(partials, out);
}